// Round 1
// baseline (190.011 us; speedup 1.0000x reference)
//
#include <hip/hip_runtime.h>

// Fused KernelWarehouse dynamic conv:
//   logits = 1x1 conv (attn_w) -> softmax over K -> grouped 3x3 conv (weight)
//   out = sum_k conv_k * softmax_k   [B,1,H,W] fp32
//
// One block per 32x32 output tile. Channel loop stages a 34x34 halo tile in
// LDS (row stride 35 floats: odd stride -> <=2 lanes/bank for the 8-rows-per-
// wave read pattern, which is conflict-free). Each thread owns a 1x4 pixel
// strip; 3x6 register patch gives 9-tap reuse across the strip.

#define C_CH 64
#define TILE 32
#define HALO 34
#define LDSS 35   // padded LDS row stride (floats)

__global__ __launch_bounds__(256, 4) void kwdc_fused(
    const float* __restrict__ x,       // [B,C,H,W]
    const float* __restrict__ weight,  // [K,C,3,3]
    const float* __restrict__ attn_w,  // [K,C]
    const float* __restrict__ attn_b,  // [K]
    float* __restrict__ out)           // [B,1,H,W]
{
    const int H = 256, W = 256;
    __shared__ float tile[HALO * LDSS];

    const int tid = threadIdx.x;
    const int tw = blockIdx.x;   // 0..7
    const int th = blockIdx.y;   // 0..7
    const int b  = blockIdx.z;   // 0..15

    const int r  = tid >> 3;     // 0..31: row within tile
    const int cg = tid & 7;      // 0..7 : col group
    const int wb = cg * 4;       // col base within tile

    const int h0 = th * TILE;
    const int w0 = tw * TILE;

    float conv[4][4];
    float logit[4][4];
#pragma unroll
    for (int k = 0; k < 4; ++k)
#pragma unroll
        for (int p = 0; p < 4; ++p) { conv[k][p] = 0.f; logit[k][p] = 0.f; }

    const float* xb = x + (size_t)b * C_CH * H * W;

    for (int c = 0; c < C_CH; ++c) {
        const float* xc = xb + (size_t)c * H * W;

        __syncthreads();   // protect tile[] reads of previous channel
        // ---- stage 34x34 halo tile (zero-padded SAME borders) ----
        for (int i = tid; i < HALO * HALO; i += 256) {
            int row = i / HALO;
            int col = i - row * HALO;
            int gh = h0 + row - 1;
            int gw = w0 + col - 1;
            float v = 0.f;
            if (gh >= 0 && gh < H && gw >= 0 && gw < W)
                v = xc[gh * W + gw];
            tile[row * LDSS + col] = v;
        }
        __syncthreads();

        // ---- 3x6 register patch for this thread's 1x4 strip ----
        float rv[3][6];
#pragma unroll
        for (int i = 0; i < 3; ++i)
#pragma unroll
            for (int j = 0; j < 6; ++j)
                rv[i][j] = tile[(r + i) * LDSS + wb + j];

        // ---- accumulate conv (9-tap) and logit (center tap) ----
#pragma unroll
        for (int k = 0; k < 4; ++k) {
            const float* wp = weight + ((k * C_CH + c) * 9);  // uniform -> s_load
            const float w00 = wp[0], w01 = wp[1], w02 = wp[2];
            const float w10 = wp[3], w11 = wp[4], w12 = wp[5];
            const float w20 = wp[6], w21 = wp[7], w22 = wp[8];
            const float aw  = attn_w[k * C_CH + c];
#pragma unroll
            for (int p = 0; p < 4; ++p) {
                float acc = conv[k][p];
                acc = fmaf(rv[0][p],     w00, acc);
                acc = fmaf(rv[0][p + 1], w01, acc);
                acc = fmaf(rv[0][p + 2], w02, acc);
                acc = fmaf(rv[1][p],     w10, acc);
                acc = fmaf(rv[1][p + 1], w11, acc);
                acc = fmaf(rv[1][p + 2], w12, acc);
                acc = fmaf(rv[2][p],     w20, acc);
                acc = fmaf(rv[2][p + 1], w21, acc);
                acc = fmaf(rv[2][p + 2], w22, acc);
                conv[k][p] = acc;
                logit[k][p] = fmaf(rv[1][p + 1], aw, logit[k][p]);
            }
        }
    }

    // ---- epilogue: softmax over K=4 + weighted mixture ----
    const float b0 = attn_b[0], b1 = attn_b[1], b2 = attn_b[2], b3 = attn_b[3];
    float4 o;
    float* op = &o.x;
#pragma unroll
    for (int p = 0; p < 4; ++p) {
        float l0 = logit[0][p] + b0;
        float l1 = logit[1][p] + b1;
        float l2 = logit[2][p] + b2;
        float l3 = logit[3][p] + b3;
        float m = fmaxf(fmaxf(l0, l1), fmaxf(l2, l3));
        float e0 = __expf(l0 - m), e1 = __expf(l1 - m);
        float e2 = __expf(l2 - m), e3 = __expf(l3 - m);
        float s = e0 + e1 + e2 + e3;
        float num = conv[0][p] * e0 + conv[1][p] * e1
                  + conv[2][p] * e2 + conv[3][p] * e3;
        op[p] = num / s;
    }
    size_t oidx = (size_t)b * H * W + (size_t)(h0 + r) * W + (w0 + wb);
    *reinterpret_cast<float4*>(out + oidx) = o;
}

extern "C" void kernel_launch(void* const* d_in, const int* in_sizes, int n_in,
                              void* d_out, int out_size, void* d_ws, size_t ws_size,
                              hipStream_t stream) {
    const float* x      = (const float*)d_in[0];
    const float* weight = (const float*)d_in[1];
    const float* attn_w = (const float*)d_in[2];
    const float* attn_b = (const float*)d_in[3];
    float* out = (float*)d_out;

    dim3 grid(8, 8, 16);   // (W/32, H/32, B)
    kwdc_fused<<<grid, 256, 0, stream>>>(x, weight, attn_w, attn_b, out);
}

// Round 3
// 130.966 us; speedup vs baseline: 1.4508x; 1.4508x over previous
//
#include <hip/hip_runtime.h>

// Fused KernelWarehouse dynamic conv, round 2 (resubmit — container died):
//   logits = 1x1 conv (attn_w) -> softmax over K=4 -> 3x3 convs -> mixture.
// R1 diagnosis: latency-bound (HBM 17%, VALU 31%) from per-channel scalar
// staging + 128 barriers. Fix: float4 staging, 4 channels per stage (32
// barriers), register double-buffer so group g+1's HBM latency hides under
// group g's compute (T14 async-split: write -> sync -> issue loads -> compute
// -> sync drains them after ~1800cyc of compute).

#define HH 256
#define WW 256
#define CH 64
#define TILE 32
#define CPB 4                    // channels staged per barrier pair
#define NG (CH / CPB)            // 16 groups
#define ROWS 34                  // tile rows incl. halo
#define NC4 10                   // float4 per staged row ([w0-4, w0+36))
#define LDSS 41                  // LDS row stride in floats (odd -> <=2-way banks)
#define CH_STRIDE (ROWS * LDSS)  // 1394 floats per channel
#define TV (CPB * ROWS * NC4)    // 1360 float4 tiles per group
#define NS 6                     // ceil(TV/256) staging regs per thread

__global__ __launch_bounds__(256, 4) void kwdc_fused(
    const float* __restrict__ x,       // [B,C,H,W]
    const float* __restrict__ weight,  // [K,C,3,3]
    const float* __restrict__ attn_w,  // [K,C]
    const float* __restrict__ attn_b,  // [K]
    float* __restrict__ out)           // [B,1,H,W]
{
    __shared__ float lds[CPB * CH_STRIDE];   // 22.3 KB

    const int tid = threadIdx.x;
    const int tw = blockIdx.x;   // 0..7
    const int th = blockIdx.y;   // 0..7
    const int b  = blockIdx.z;   // 0..15

    const int r  = tid >> 3;     // 0..31 row in tile
    const int cg = tid & 7;      // col group
    const int wb = cg * 4;       // col base

    const int h0 = th * TILE;
    const int w0 = tw * TILE;

    const float* xb = x + (size_t)b * CH * HH * WW;

    // ---- per-s staging metadata (tid-dependent only) ----
    int  s_ch[NS];      // channel within group
    int  s_gofs[NS];    // offset within a channel plane (valid only if s_val)
    int  s_lofs[NS];    // LDS float offset
    bool s_val[NS];     // load from global (in-bounds)
    bool s_act[NS];     // participate at all
#pragma unroll
    for (int s = 0; s < NS; ++s) {
        int i = tid + s * 256;
        bool act = i < TV;
        int col4  = i % NC4;
        int rowch = i / NC4;
        int row   = rowch % ROWS;
        int ch    = rowch / ROWS;
        int gh  = h0 + row - 1;
        int gw0 = w0 - 4 + col4 * 4;      // always 16B-aligned; fully in or out
        s_act[s]  = act;
        s_val[s]  = act && ((unsigned)gh < HH) && ((unsigned)gw0 < WW);
        s_gofs[s] = gh * WW + gw0;
        s_lofs[s] = ch * CH_STRIDE + row * LDSS + col4 * 4;
        s_ch[s]   = ch;
    }

    float4 stg[NS];

    // issue global loads for group g into stg
    auto load_group = [&](int g) {
#pragma unroll
        for (int s = 0; s < NS; ++s) {
            float4 v = {0.f, 0.f, 0.f, 0.f};
            if (s_val[s]) {
                const float* p = xb + (size_t)(g * CPB + s_ch[s]) * (HH * WW) + s_gofs[s];
                v = *reinterpret_cast<const float4*>(p);
            }
            stg[s] = v;
        }
    };

    float conv[4][4];
    float logit[4][4];
#pragma unroll
    for (int k = 0; k < 4; ++k)
#pragma unroll
        for (int p = 0; p < 4; ++p) { conv[k][p] = 0.f; logit[k][p] = 0.f; }

    load_group(0);

    for (int g = 0; g < NG; ++g) {
        // ---- write staged regs -> LDS (compiler waits vmcnt as needed) ----
#pragma unroll
        for (int s = 0; s < NS; ++s) {
            if (s_act[s]) {
                float* q = &lds[s_lofs[s]];
                q[0] = stg[s].x; q[1] = stg[s].y; q[2] = stg[s].z; q[3] = stg[s].w;
            }
        }
        __syncthreads();

        // ---- prefetch next group into regs; latency hides under compute ----
        if (g + 1 < NG) load_group(g + 1);

        // ---- compute 4 channels from LDS ----
#pragma unroll
        for (int c = 0; c < CPB; ++c) {
            const int gc = g * CPB + c;
            const float* tp = &lds[c * CH_STRIDE + r * LDSS + wb + 3];
            float rv[3][6];
#pragma unroll
            for (int i = 0; i < 3; ++i)
#pragma unroll
                for (int j = 0; j < 6; ++j)
                    rv[i][j] = tp[i * LDSS + j];

#pragma unroll
            for (int k = 0; k < 4; ++k) {
                const float* wp = weight + (k * CH + gc) * 9;   // wave-uniform
                const float w00 = wp[0], w01 = wp[1], w02 = wp[2];
                const float w10 = wp[3], w11 = wp[4], w12 = wp[5];
                const float w20 = wp[6], w21 = wp[7], w22 = wp[8];
                const float aw  = attn_w[k * CH + gc];
#pragma unroll
                for (int p = 0; p < 4; ++p) {
                    float acc = conv[k][p];
                    acc = fmaf(rv[0][p],     w00, acc);
                    acc = fmaf(rv[0][p + 1], w01, acc);
                    acc = fmaf(rv[0][p + 2], w02, acc);
                    acc = fmaf(rv[1][p],     w10, acc);
                    acc = fmaf(rv[1][p + 1], w11, acc);
                    acc = fmaf(rv[1][p + 2], w12, acc);
                    acc = fmaf(rv[2][p],     w20, acc);
                    acc = fmaf(rv[2][p + 1], w21, acc);
                    acc = fmaf(rv[2][p + 2], w22, acc);
                    conv[k][p] = acc;
                    logit[k][p] = fmaf(rv[1][p + 1], aw, logit[k][p]);
                }
            }
        }
        __syncthreads();   // LDS reads done + drains next group's loads
    }

    // ---- epilogue: softmax over K=4 + mixture ----
    const float b0 = attn_b[0], b1 = attn_b[1], b2 = attn_b[2], b3 = attn_b[3];
    float4 o;
    float* op = &o.x;
#pragma unroll
    for (int p = 0; p < 4; ++p) {
        float l0 = logit[0][p] + b0;
        float l1 = logit[1][p] + b1;
        float l2 = logit[2][p] + b2;
        float l3 = logit[3][p] + b3;
        float m = fmaxf(fmaxf(l0, l1), fmaxf(l2, l3));
        float e0 = __expf(l0 - m), e1 = __expf(l1 - m);
        float e2 = __expf(l2 - m), e3 = __expf(l3 - m);
        float s = e0 + e1 + e2 + e3;
        float num = conv[0][p] * e0 + conv[1][p] * e1
                  + conv[2][p] * e2 + conv[3][p] * e3;
        op[p] = num / s;
    }
    size_t oidx = (size_t)b * HH * WW + (size_t)(h0 + r) * WW + (w0 + wb);
    *reinterpret_cast<float4*>(out + oidx) = o;
}

extern "C" void kernel_launch(void* const* d_in, const int* in_sizes, int n_in,
                              void* d_out, int out_size, void* d_ws, size_t ws_size,
                              hipStream_t stream) {
    const float* x      = (const float*)d_in[0];
    const float* weight = (const float*)d_in[1];
    const float* attn_w = (const float*)d_in[2];
    const float* attn_b = (const float*)d_in[3];
    float* out = (float*)d_out;

    dim3 grid(8, 8, 16);   // (W/32, H/32, B)
    kwdc_fused<<<grid, 256, 0, stream>>>(x, weight, attn_w, attn_b, out);
}